// Round 1
// baseline (3791.007 us; speedup 1.0000x reference)
//
#include <hip/hip_runtime.h>
#include <hip/hip_bf16.h>
#include <cstdint>
#include <cstddef>

// Problem constants
#define BB 4
#define SS 2048
#define DIMM 1024
#define NH 16
#define DH 64
#define MTOT (BB * SS)   // 8192

// ============================================================================
// GEMM: Y = A @ W + bias
//  A logical [8192 x 1024].
//   AMODE 0: plain row-major [M, K]
//   AMODE 1: head-interleaved [B, H, S, Dh]  (k = h*64+d)
//  W: [1024 x 1024] row-major. bias: [1024].
//  Y:
//   OMODE 0: head-interleaved [B, H, S, Dh]  (n = h*64+d)
//   OMODE 1: plain row-major [M, N]
// Tile 128x128, BK=16, 256 threads, 8x8 micro-tile (2x2 blocks of 4x4 at +64).
// ============================================================================
template<int AMODE, int OMODE>
__global__ __launch_bounds__(256)
void gemm_bias_kernel(const float* __restrict__ A, const float* __restrict__ W,
                      const float* __restrict__ bias, float* __restrict__ Y)
{
    __shared__ float As[16][128];   // As[k][m] (transposed A tile)
    __shared__ float Bs[16][128];   // Bs[k][n]

    const int tid = threadIdx.x;
    const int tx = tid & 15;
    const int ty = tid >> 4;
    const int m0 = blockIdx.y * 128;
    const int n0 = blockIdx.x * 128;

    float acc[8][8];
#pragma unroll
    for (int i = 0; i < 8; ++i)
#pragma unroll
        for (int j = 0; j < 8; ++j) acc[i][j] = 0.0f;

    for (int k0 = 0; k0 < DIMM; k0 += 16) {
        // ---- load A tile: 128 rows x 16 k (one float4 per thread per half)
#pragma unroll
        for (int it = 0; it < 2; ++it) {
            const int r  = (tid >> 2) + it * 64;
            const int c4 = (tid & 3) * 4;
            const int m  = m0 + r;
            const int k  = k0 + c4;
            float4 a4;
            if (AMODE == 0) {
                a4 = *reinterpret_cast<const float4*>(&A[(size_t)m * DIMM + k]);
            } else {
                const int b = m >> 11, s = m & 2047;
                const int h = k >> 6,  d = k & 63;
                a4 = *reinterpret_cast<const float4*>(
                        &A[(((size_t)(b * NH + h)) * SS + s) * DH + d]);
            }
            As[c4 + 0][r] = a4.x;
            As[c4 + 1][r] = a4.y;
            As[c4 + 2][r] = a4.z;
            As[c4 + 3][r] = a4.w;
        }
        // ---- load W tile: 16 k x 128 n
#pragma unroll
        for (int it = 0; it < 2; ++it) {
            const int r  = (tid >> 5) + it * 8;
            const int c4 = (tid & 31) * 4;
            *reinterpret_cast<float4*>(&Bs[r][c4]) =
                *reinterpret_cast<const float4*>(&W[(size_t)(k0 + r) * DIMM + n0 + c4]);
        }
        __syncthreads();

#pragma unroll
        for (int kk = 0; kk < 16; ++kk) {
            const float4 a0 = *reinterpret_cast<const float4*>(&As[kk][ty * 4]);
            const float4 a1 = *reinterpret_cast<const float4*>(&As[kk][64 + ty * 4]);
            const float4 b0 = *reinterpret_cast<const float4*>(&Bs[kk][tx * 4]);
            const float4 b1 = *reinterpret_cast<const float4*>(&Bs[kk][64 + tx * 4]);
            const float ar[8] = {a0.x, a0.y, a0.z, a0.w, a1.x, a1.y, a1.z, a1.w};
            const float br[8] = {b0.x, b0.y, b0.z, b0.w, b1.x, b1.y, b1.z, b1.w};
#pragma unroll
            for (int i = 0; i < 8; ++i)
#pragma unroll
                for (int j = 0; j < 8; ++j)
                    acc[i][j] = fmaf(ar[i], br[j], acc[i][j]);
        }
        __syncthreads();
    }

    // ---- epilogue: add bias, store
    const float4 bias0 = *reinterpret_cast<const float4*>(&bias[n0 + tx * 4]);
    const float4 bias1 = *reinterpret_cast<const float4*>(&bias[n0 + 64 + tx * 4]);
    const float bb[8] = {bias0.x, bias0.y, bias0.z, bias0.w,
                         bias1.x, bias1.y, bias1.z, bias1.w};

#pragma unroll
    for (int i = 0; i < 8; ++i) {
        const int row = m0 + ((i < 4) ? (ty * 4 + i) : (64 + ty * 4 + (i - 4)));
#pragma unroll
        for (int jq = 0; jq < 2; ++jq) {
            const int col = n0 + jq * 64 + tx * 4;
            float4 v;
            v.x = acc[i][jq * 4 + 0] + bb[jq * 4 + 0];
            v.y = acc[i][jq * 4 + 1] + bb[jq * 4 + 1];
            v.z = acc[i][jq * 4 + 2] + bb[jq * 4 + 2];
            v.w = acc[i][jq * 4 + 3] + bb[jq * 4 + 3];
            if (OMODE == 1) {
                *reinterpret_cast<float4*>(&Y[(size_t)row * DIMM + col]) = v;
            } else {
                const int b = row >> 11, s = row & 2047;
                const int h = col >> 6,  d = col & 63;
                *reinterpret_cast<float4*>(
                    &Y[(((size_t)(b * NH + h)) * SS + s) * DH + d]) = v;
            }
        }
    }
}

// ============================================================================
// Flash attention, fp32. One block per (h, q-tile(64), b). 256 threads.
// Qh/Kh/Vh in [B, H, S, Dh]. Output written in-place over QO (each block only
// writes the Q rows it already consumed into LDS).
// ============================================================================
__global__ __launch_bounds__(256)
void flash_kernel(float* QO, const float* __restrict__ Kh,
                  const float* __restrict__ Vh, const int* __restrict__ mask)
{
    const int h  = blockIdx.x;
    const int qt = blockIdx.y;
    const int b  = blockIdx.z;
    const int tid = threadIdx.x;
    const int tx = tid & 15;
    const int ty = tid >> 4;

    __shared__ float Qt[64][68];   // [d][q]
    __shared__ float Kt[64][68];   // [d][k]
    __shared__ float Vs[64][68];   // [k][d]
    __shared__ float St[64][68];   // [k][q]  (P transposed)
    __shared__ float redm[4][64];
    __shared__ float reds[4][64];
    __shared__ float mrow[64], lrow[64], arow[64];

    const int q0 = qt * 64;
    const size_t hb = ((size_t)(b * NH + h)) * (size_t)(SS * DH);

    // load Q tile transposed
#pragma unroll
    for (int it = 0; it < 4; ++it) {
        const int r  = (tid >> 4) + it * 16;
        const int d4 = (tid & 15) * 4;
        const float4 t = *reinterpret_cast<const float4*>(
            &QO[hb + (size_t)(q0 + r) * DH + d4]);
        Qt[d4 + 0][r] = t.x; Qt[d4 + 1][r] = t.y;
        Qt[d4 + 2][r] = t.z; Qt[d4 + 3][r] = t.w;
    }
    if (tid < 64) { mrow[tid] = -3.0e38f; lrow[tid] = 0.0f; }

    float oacc[4][4];
#pragma unroll
    for (int i = 0; i < 4; ++i)
#pragma unroll
        for (int j = 0; j < 4; ++j) oacc[i][j] = 0.0f;

    const int qpart = tid & 63;
    const int part  = tid >> 6;

    for (int k0 = 0; k0 < SS; k0 += 64) {
        __syncthreads();   // previous iter's Phase F done before overwriting tiles

        // ---- load K (transposed) + V (direct)
#pragma unroll
        for (int it = 0; it < 4; ++it) {
            const int r  = (tid >> 4) + it * 16;
            const int d4 = (tid & 15) * 4;
            const float4 tk = *reinterpret_cast<const float4*>(
                &Kh[hb + (size_t)(k0 + r) * DH + d4]);
            Kt[d4 + 0][r] = tk.x; Kt[d4 + 1][r] = tk.y;
            Kt[d4 + 2][r] = tk.z; Kt[d4 + 3][r] = tk.w;
            const float4 tv = *reinterpret_cast<const float4*>(
                &Vh[hb + (size_t)(k0 + r) * DH + d4]);
            *reinterpret_cast<float4*>(&Vs[r][d4]) = tv;
        }
        __syncthreads();

        // ---- Phase A: S = Q.K^T ; thread owns k-rows ty*4+i, q-cols tx*4+j
        float sc[4][4];
#pragma unroll
        for (int i = 0; i < 4; ++i)
#pragma unroll
            for (int j = 0; j < 4; ++j) sc[i][j] = 0.0f;

#pragma unroll
        for (int d = 0; d < 64; ++d) {
            const float4 qa = *reinterpret_cast<const float4*>(&Qt[d][tx * 4]);
            const float4 kb = *reinterpret_cast<const float4*>(&Kt[d][ty * 4]);
            const float qr[4] = {qa.x, qa.y, qa.z, qa.w};
            const float kr[4] = {kb.x, kb.y, kb.z, kb.w};
#pragma unroll
            for (int i = 0; i < 4; ++i)
#pragma unroll
                for (int j = 0; j < 4; ++j)
                    sc[i][j] = fmaf(kr[i], qr[j], sc[i][j]);
        }

        // scale + mask (masked entries become exactly -1e9, matching reference)
#pragma unroll
        for (int j = 0; j < 4; ++j) {
            const int q = q0 + tx * 4 + j;
            const int4 mk = *reinterpret_cast<const int4*>(
                &mask[((size_t)b * SS + q) * SS + k0 + ty * 4]);
            const int mr[4] = {mk.x, mk.y, mk.z, mk.w};
#pragma unroll
            for (int i = 0; i < 4; ++i)
                sc[i][j] = (mr[i] == 0) ? -1.0e9f : sc[i][j] * 0.125f;
        }

        // store St[k][q] (float4 along q)
#pragma unroll
        for (int i = 0; i < 4; ++i) {
            float4 v;
            v.x = sc[i][0]; v.y = sc[i][1]; v.z = sc[i][2]; v.w = sc[i][3];
            *reinterpret_cast<float4*>(&St[ty * 4 + i][tx * 4]) = v;
        }
        __syncthreads();

        // ---- Phase B: partial max over k per q
        {
            float pm = -3.0e38f;
#pragma unroll
            for (int kk = 0; kk < 16; ++kk)
                pm = fmaxf(pm, St[part * 16 + kk][qpart]);
            redm[part][qpart] = pm;
        }
        __syncthreads();

        // ---- Phase C: new running max + rescale factor
        if (tid < 64) {
            const float mo = mrow[tid];
            float mn = fmaxf(fmaxf(redm[0][tid], redm[1][tid]),
                             fmaxf(redm[2][tid], redm[3][tid]));
            mn = fmaxf(mo, mn);
            arow[tid] = __expf(mo - mn);
            mrow[tid] = mn;
        }
        __syncthreads();

        // ---- Phase D: exponentiate in place + partial sums
        {
            const float mn = mrow[qpart];
            float ps = 0.0f;
#pragma unroll
            for (int kk = 0; kk < 16; ++kk) {
                const float e = __expf(St[part * 16 + kk][qpart] - mn);
                St[part * 16 + kk][qpart] = e;
                ps += e;
            }
            reds[part][qpart] = ps;
        }
        __syncthreads();

        // ---- Phase E: update denominator
        if (tid < 64)
            lrow[tid] = arow[tid] * lrow[tid]
                      + reds[0][tid] + reds[1][tid] + reds[2][tid] + reds[3][tid];

        // ---- Phase F: rescale O, accumulate P.V
        {
            const float av[4] = {arow[ty * 4 + 0], arow[ty * 4 + 1],
                                 arow[ty * 4 + 2], arow[ty * 4 + 3]};
#pragma unroll
            for (int i = 0; i < 4; ++i)
#pragma unroll
                for (int j = 0; j < 4; ++j) oacc[i][j] *= av[i];

#pragma unroll
            for (int k = 0; k < 64; ++k) {
                const float4 p  = *reinterpret_cast<const float4*>(&St[k][ty * 4]);
                const float4 vv = *reinterpret_cast<const float4*>(&Vs[k][tx * 4]);
                const float pr[4] = {p.x, p.y, p.z, p.w};
                const float vr[4] = {vv.x, vv.y, vv.z, vv.w};
#pragma unroll
                for (int i = 0; i < 4; ++i)
#pragma unroll
                    for (int j = 0; j < 4; ++j)
                        oacc[i][j] = fmaf(pr[i], vr[j], oacc[i][j]);
            }
        }
    }
    __syncthreads();   // lrow final

    // ---- epilogue: normalize, write context over the Q region
#pragma unroll
    for (int i = 0; i < 4; ++i) {
        const float inv = 1.0f / lrow[ty * 4 + i];
        float4 v;
        v.x = oacc[i][0] * inv; v.y = oacc[i][1] * inv;
        v.z = oacc[i][2] * inv; v.w = oacc[i][3] * inv;
        *reinterpret_cast<float4*>(&QO[hb + (size_t)(q0 + ty * 4 + i) * DH + tx * 4]) = v;
    }
}

// ============================================================================
extern "C" void kernel_launch(void* const* d_in, const int* in_sizes, int n_in,
                              void* d_out, int out_size, void* d_ws, size_t ws_size,
                              hipStream_t stream)
{
    const float* q    = (const float*)d_in[0];
    const float* k    = (const float*)d_in[1];
    const float* v    = (const float*)d_in[2];
    const float* Wq   = (const float*)d_in[3];
    const float* bq   = (const float*)d_in[4];
    const float* Wk   = (const float*)d_in[5];
    const float* bk   = (const float*)d_in[6];
    const float* Wv   = (const float*)d_in[7];
    const float* bv   = (const float*)d_in[8];
    const float* Wo   = (const float*)d_in[9];
    const float* bo   = (const float*)d_in[10];
    const int*   mask = (const int*)d_in[11];
    float* out = (float*)d_out;

    // workspace: Qh, Kh, Vh each [B,H,S,Dh] fp32 = 32 MB (context written over Qh)
    float* Qh = (float*)d_ws;
    float* Kh = Qh + (size_t)BB * NH * SS * DH;
    float* Vh = Kh + (size_t)BB * NH * SS * DH;

    dim3 gblock(256);
    dim3 ggrid(DIMM / 128, MTOT / 128);   // (8, 64)

    gemm_bias_kernel<0, 0><<<ggrid, gblock, 0, stream>>>(q, Wq, bq, Qh);
    gemm_bias_kernel<0, 0><<<ggrid, gblock, 0, stream>>>(k, Wk, bk, Kh);
    gemm_bias_kernel<0, 0><<<ggrid, gblock, 0, stream>>>(v, Wv, bv, Vh);

    dim3 fgrid(NH, SS / 64, BB);          // (16, 32, 4) = 2048 blocks
    flash_kernel<<<fgrid, gblock, 0, stream>>>(Qh, Kh, Vh, mask);

    gemm_bias_kernel<1, 1><<<ggrid, gblock, 0, stream>>>(Qh, Wo, bo, out);
}

// Round 2
// 513.923 us; speedup vs baseline: 7.3766x; 7.3766x over previous
//
#include <hip/hip_runtime.h>
#include <cstdint>
#include <cstddef>

#define BB 4
#define SS 2048
#define DIMM 1024
#define NH 16
#define DH 64
#define MT 8192   // B*S

typedef __attribute__((ext_vector_type(8))) short bf16x8;
typedef __attribute__((ext_vector_type(4))) float f32x4;
typedef __attribute__((ext_vector_type(4))) unsigned short u16x4;

#define MFMA_BF16(a, b, c) __builtin_amdgcn_mfma_f32_16x16x32_bf16(a, b, c, 0, 0, 0)

// float -> bf16 bits, round-nearest-even (branchless; inputs finite)
__device__ __forceinline__ unsigned short f2b(float f) {
    unsigned int u = __float_as_uint(f);
    u += 0x7fffu + ((u >> 16) & 1u);
    return (unsigned short)(u >> 16);
}

// async 16B global -> LDS (dest = wave-uniform base + lane*16)
__device__ __forceinline__ void gload16(const void* g, void* l) {
    __builtin_amdgcn_global_load_lds(
        (const __attribute__((address_space(1))) unsigned int*)g,
        (__attribute__((address_space(3))) unsigned int*)l, 16, 0, 0);
}

// XOR-swizzled byte offset for a [64 rows][64 bf16] tile (8 chunks of 16B/row)
__device__ __forceinline__ int swzb(int row, int cb) {
    return row * 128 + (((cb) ^ (row & 7)) << 4);
}

// ============================================================================
// W [1024][1024] fp32 (k-major rows) -> WT [1024][1024] bf16 as [n][k]
// ============================================================================
__global__ __launch_bounds__(256)
void wtrans_kernel(const float* __restrict__ W, unsigned short* __restrict__ WT)
{
    __shared__ unsigned short T[64][72];
    const int tid = threadIdx.x;
    const int k0 = blockIdx.y * 64, n0 = blockIdx.x * 64;
#pragma unroll
    for (int it = 0; it < 4; ++it) {
        const int c = tid + it * 256;
        const int row = c >> 4, c4 = (c & 15) * 4;
        const float4 v = *reinterpret_cast<const float4*>(&W[(size_t)(k0 + row) * DIMM + n0 + c4]);
        T[row][c4 + 0] = f2b(v.x);
        T[row][c4 + 1] = f2b(v.y);
        T[row][c4 + 2] = f2b(v.z);
        T[row][c4 + 3] = f2b(v.w);
    }
    __syncthreads();
#pragma unroll
    for (int it = 0; it < 4; ++it) {
        const int c = tid + it * 256;
        const int n = c >> 4, k4 = (c & 15) * 4;
        u16x4 o;
        o[0] = T[k4 + 0][n];
        o[1] = T[k4 + 1][n];
        o[2] = T[k4 + 2][n];
        o[3] = T[k4 + 3][n];
        *reinterpret_cast<u16x4*>(&WT[(size_t)(n0 + n) * DIMM + k0 + k4]) = o;
    }
}

// ============================================================================
// GEMM, 128x128 tile, BK=32, 4 waves (2x2), 16x16x32 bf16 MFMA, fp32 accum.
// MODE 0: A = fp32 row-major [8192][1024] (converted in-stage),
//         Y = bf16 head-interleaved [B,H,S,Dh], bias fp32.
// MODE 1: A = bf16 head-interleaved (ctx), Y = fp32 row-major [8192][1024].
// BT = bf16 [n][k] (pre-transposed weights).
// ============================================================================
template<int MODE>
__global__ __launch_bounds__(256)
void gemm_kernel(const void* __restrict__ Ax, const unsigned short* __restrict__ BT,
                 const float* __restrict__ bias, void* __restrict__ Y)
{
    __shared__ __align__(16) unsigned short As[128 * 32];
    __shared__ __align__(16) unsigned short Bs[128 * 32];
    const int tid = threadIdx.x;
    const int w = tid >> 6, l = tid & 63;
    const int g = l >> 4, li = l & 15;
    const int m0 = blockIdx.y * 128, n0 = blockIdx.x * 128;
    const int wm0 = (w >> 1) * 64, wn0 = (w & 1) * 64;

    const f32x4 fzero = {0.f, 0.f, 0.f, 0.f};
    f32x4 acc[4][4];
#pragma unroll
    for (int i = 0; i < 4; ++i)
#pragma unroll
        for (int j = 0; j < 4; ++j) acc[i][j] = fzero;

    for (int k0 = 0; k0 < DIMM; k0 += 32) {
        // ---- stage A tile [128 m][32 k]
        if (MODE == 0) {
            const float* A = (const float*)Ax;
#pragma unroll
            for (int it = 0; it < 2; ++it) {
                const int c = tid + it * 256;
                const int row = c >> 2, cb = c & 3;
                const float* src = &A[(size_t)(m0 + row) * DIMM + k0 + cb * 8];
                const float4 lo = *reinterpret_cast<const float4*>(src);
                const float4 hi = *reinterpret_cast<const float4*>(src + 4);
                bf16x8 vv;
                vv[0] = (short)f2b(lo.x); vv[1] = (short)f2b(lo.y);
                vv[2] = (short)f2b(lo.z); vv[3] = (short)f2b(lo.w);
                vv[4] = (short)f2b(hi.x); vv[5] = (short)f2b(hi.y);
                vv[6] = (short)f2b(hi.z); vv[7] = (short)f2b(hi.w);
                *reinterpret_cast<bf16x8*>(&As[c * 8]) = vv;
            }
        } else {
            const unsigned short* A = (const unsigned short*)Ax;
            const int h = k0 >> 6;
#pragma unroll
            for (int it = 0; it < 2; ++it) {
                const int c = it * 256 + w * 64 + l;
                const int row = c >> 2, cb = c & 3;
                const int m = m0 + row;
                const int bb = m >> 11, s = m & 2047;
                const unsigned short* src =
                    &A[(((size_t)(bb * NH + h)) * SS + s) * DH + (k0 & 63) + cb * 8];
                gload16(src, &As[(it * 256 + w * 64) * 8]);
            }
        }
        // ---- stage B tile [128 n][32 k]
#pragma unroll
        for (int it = 0; it < 2; ++it) {
            const int c = it * 256 + w * 64 + l;
            const int row = c >> 2, cb = c & 3;
            const unsigned short* src = &BT[(size_t)(n0 + row) * DIMM + k0 + cb * 8];
            gload16(src, &Bs[(it * 256 + w * 64) * 8]);
        }
        __syncthreads();

        bf16x8 af[4], bf[4];
#pragma unroll
        for (int mb = 0; mb < 4; ++mb)
            af[mb] = *reinterpret_cast<const bf16x8*>(&As[(wm0 + mb * 16 + li) * 32 + g * 8]);
#pragma unroll
        for (int nb = 0; nb < 4; ++nb)
            bf[nb] = *reinterpret_cast<const bf16x8*>(&Bs[(wn0 + nb * 16 + li) * 32 + g * 8]);
#pragma unroll
        for (int mb = 0; mb < 4; ++mb)
#pragma unroll
            for (int nb = 0; nb < 4; ++nb)
                acc[mb][nb] = MFMA_BF16(af[mb], bf[nb], acc[mb][nb]);
        __syncthreads();
    }

    // ---- epilogue: bias + store. D layout: row=(l>>4)*4+r, col=l&15 (m89)
    float bv4[4];
#pragma unroll
    for (int nb = 0; nb < 4; ++nb)
        bv4[nb] = bias[n0 + wn0 + nb * 16 + li];

#pragma unroll
    for (int mb = 0; mb < 4; ++mb) {
#pragma unroll
        for (int r = 0; r < 4; ++r) {
            const int row_g = m0 + wm0 + mb * 16 + g * 4 + r;
#pragma unroll
            for (int nb = 0; nb < 4; ++nb) {
                const int col = n0 + wn0 + nb * 16 + li;
                const float val = acc[mb][nb][r] + bv4[nb];
                if (MODE == 0) {
                    const int bb = row_g >> 11, s = row_g & 2047;
                    const int hh = col >> 6, dd = col & 63;
                    ((unsigned short*)Y)[(((size_t)(bb * NH + hh)) * SS + s) * DH + dd] = f2b(val);
                } else {
                    ((float*)Y)[(size_t)row_g * DIMM + col] = val;
                }
            }
        }
    }
}

// ============================================================================
// Flash attention, bf16 MFMA, fp32 accum/softmax.
// Block = (h, q-tile 64, b), 256 threads = 4 waves; wave w owns q rows
// [16w, 16w+16). Per 64-k tile: S = Q·K^T (Q frags in regs, K in swizzled
// LDS), online softmax in regs (shfl_xor over 16-lane groups), P -> swizzled
// LDS bf16, O^T = V^T·P^T (V^T in swizzled LDS).
// ============================================================================
__global__ __launch_bounds__(256)
void flash_kernel(const unsigned short* __restrict__ Qh, const unsigned short* __restrict__ Kh,
                  const unsigned short* __restrict__ Vh, const int* __restrict__ mask,
                  unsigned short* __restrict__ Ctx)
{
    const int h = blockIdx.x, qt = blockIdx.y, b = blockIdx.z;
    const int tid = threadIdx.x;
    const int w = tid >> 6, l = tid & 63;
    const int g = l >> 4, li = l & 15;

    __shared__ __align__(16) unsigned short Ks[64 * 64];   // swizzled [k][d]
    __shared__ __align__(16) unsigned short Vt[64 * 64];   // swizzled [d][k]
    __shared__ __align__(16) unsigned short Ps[64 * 64];   // swizzled [q][k]
    __shared__ float a_arr[64], l_arr[64];

    const int q0 = qt * 64;
    const size_t hb = ((size_t)(b * NH + h)) * (size_t)(SS * DH);

    // Q fragments in registers (reused across all k-tiles)
    bf16x8 qf0, qf1;
    {
        const unsigned short* qp = &Qh[hb + (size_t)(q0 + w * 16 + li) * DH + g * 8];
        qf0 = *reinterpret_cast<const bf16x8*>(qp);
        qf1 = *reinterpret_cast<const bf16x8*>(qp + 32);
    }

    const f32x4 fzero = {0.f, 0.f, 0.f, 0.f};
    f32x4 oacc[4];
#pragma unroll
    for (int mb = 0; mb < 4; ++mb) oacc[mb] = fzero;
    float mrun[4], lrun[4];
#pragma unroll
    for (int r = 0; r < 4; ++r) { mrun[r] = -3.0e38f; lrun[r] = 0.0f; }

    for (int k0 = 0; k0 < SS; k0 += 64) {
        __syncthreads();   // all waves done reading Ks/Vt of previous tile

        // ---- stage K tile (8KB contiguous) via global_load_lds, src pre-swizzled
        {
            const unsigned short* tile = &Kh[hb + (size_t)k0 * DH];
#pragma unroll
            for (int it = 0; it < 2; ++it) {
                const int cd = it * 256 + w * 64 + l;   // dest chunk (linear)
                const int row = cd >> 3, cbp = cd & 7;
                const int cbs = cbp ^ (row & 7);        // source chunk for this slot
                gload16(tile + (row * 8 + cbs) * 8, &Ks[(it * 256 + w * 64) * 8]);
            }
        }
        // ---- stage V transposed into Vt[d][k] (reg-stage, swizzled writes)
        {
            const unsigned short* tile = &Vh[hb + (size_t)k0 * DH];
#pragma unroll
            for (int it = 0; it < 2; ++it) {
                const int c = it * 256 + tid;
                const int kk = c >> 3, d0 = (c & 7) * 8;
                const bf16x8 vv = *reinterpret_cast<const bf16x8*>(tile + kk * 64 + d0);
#pragma unroll
                for (int i = 0; i < 8; ++i) {
                    *(unsigned short*)((char*)Vt + swzb(d0 + i, kk >> 3) + (kk & 7) * 2) =
                        (unsigned short)vv[i];
                }
            }
        }
        __syncthreads();

        // ---- S = Q·K^T : wave computes 16 q rows x 64 k cols
        f32x4 sc[4];
#pragma unroll
        for (int nb = 0; nb < 4; ++nb) sc[nb] = fzero;
#pragma unroll
        for (int nb = 0; nb < 4; ++nb) {
            const bf16x8 kf0 = *reinterpret_cast<const bf16x8*>((const char*)Ks + swzb(nb * 16 + li, g));
            const bf16x8 kf1 = *reinterpret_cast<const bf16x8*>((const char*)Ks + swzb(nb * 16 + li, 4 + g));
            sc[nb] = MFMA_BF16(qf0, kf0, sc[nb]);
            sc[nb] = MFMA_BF16(qf1, kf1, sc[nb]);
        }

        // ---- mask + scale + online softmax (rows g*4+r, cols nb*16+li)
        float ev[4][4];
        float af_[4];
        const int qb = q0 + w * 16 + g * 4;
#pragma unroll
        for (int r = 0; r < 4; ++r) {
            float mx = -3.0e38f;
#pragma unroll
            for (int nb = 0; nb < 4; ++nb) {
                const int mval = mask[((size_t)b * SS + (qb + r)) * SS + k0 + nb * 16 + li];
                const float s = (mval == 0) ? -1.0e9f : sc[nb][r] * 0.125f;
                ev[nb][r] = s;
                mx = fmaxf(mx, s);
            }
            mx = fmaxf(mx, __shfl_xor(mx, 1));
            mx = fmaxf(mx, __shfl_xor(mx, 2));
            mx = fmaxf(mx, __shfl_xor(mx, 4));
            mx = fmaxf(mx, __shfl_xor(mx, 8));
            const float mn = fmaxf(mrun[r], mx);
            const float a = __expf(mrun[r] - mn);
            mrun[r] = mn;
            float ps = 0.0f;
#pragma unroll
            for (int nb = 0; nb < 4; ++nb) {
                const float e = __expf(ev[nb][r] - mn);
                ev[nb][r] = e;
                ps += e;
            }
            ps += __shfl_xor(ps, 1);
            ps += __shfl_xor(ps, 2);
            ps += __shfl_xor(ps, 4);
            ps += __shfl_xor(ps, 8);
            lrun[r] = a * lrun[r] + ps;
            af_[r] = a;
        }
        if (li < 4) {
            const float a = (li == 0) ? af_[0] : (li == 1) ? af_[1] : (li == 2) ? af_[2] : af_[3];
            a_arr[w * 16 + g * 4 + li] = a;
        }
        // ---- write P (bf16, swizzled [q][k]); rows are wave-private
#pragma unroll
        for (int r = 0; r < 4; ++r) {
            const int qrow = w * 16 + g * 4 + r;
#pragma unroll
            for (int nb = 0; nb < 4; ++nb) {
                const int kk = nb * 16 + li;
                *(unsigned short*)((char*)Ps + swzb(qrow, kk >> 3) + (kk & 7) * 2) = f2b(ev[nb][r]);
            }
        }
        // ---- rescale O, accumulate O^T += V^T·P^T
        const float av = a_arr[w * 16 + li];
#pragma unroll
        for (int mb = 0; mb < 4; ++mb) oacc[mb] = oacc[mb] * av;
#pragma unroll
        for (int ks = 0; ks < 2; ++ks) {
            const bf16x8 pf = *reinterpret_cast<const bf16x8*>(
                (const char*)Ps + swzb(w * 16 + li, ks * 4 + g));
#pragma unroll
            for (int mb = 0; mb < 4; ++mb) {
                const bf16x8 vf = *reinterpret_cast<const bf16x8*>(
                    (const char*)Vt + swzb(mb * 16 + li, ks * 4 + g));
                oacc[mb] = MFMA_BF16(vf, pf, oacc[mb]);
            }
        }
    }

    // ---- finalize: normalize, transpose via LDS (reuse Ps), coalesced store
    if (li < 4) {
        const float lv = (li == 0) ? lrun[0] : (li == 1) ? lrun[1] : (li == 2) ? lrun[2] : lrun[3];
        l_arr[w * 16 + g * 4 + li] = lv;
    }
    const float linv = 1.0f / l_arr[w * 16 + li];
#pragma unroll
    for (int mb = 0; mb < 4; ++mb) {
#pragma unroll
        for (int r = 0; r < 4; ++r) {
            const int dd = mb * 16 + g * 4 + r;
            *(unsigned short*)((char*)Ps + swzb(w * 16 + li, dd >> 3) + (dd & 7) * 2) =
                f2b(oacc[mb][r] * linv);
        }
    }
#pragma unroll
    for (int it = 0; it < 2; ++it) {
        const int c = it * 64 + l;
        const int qrow = w * 16 + (c >> 3), cb = c & 7;
        const bf16x8 ov = *reinterpret_cast<const bf16x8*>((const char*)Ps + swzb(qrow, cb));
        *reinterpret_cast<bf16x8*>(&Ctx[hb + (size_t)(q0 + qrow) * DH + cb * 8]) = ov;
    }
}

// ============================================================================
extern "C" void kernel_launch(void* const* d_in, const int* in_sizes, int n_in,
                              void* d_out, int out_size, void* d_ws, size_t ws_size,
                              hipStream_t stream)
{
    const float* q  = (const float*)d_in[0];
    const float* k  = (const float*)d_in[1];
    const float* v  = (const float*)d_in[2];
    const float* Wq = (const float*)d_in[3];
    const float* bq = (const float*)d_in[4];
    const float* Wk = (const float*)d_in[5];
    const float* bk = (const float*)d_in[6];
    const float* Wv = (const float*)d_in[7];
    const float* bv = (const float*)d_in[8];
    const float* Wo = (const float*)d_in[9];
    const float* bo = (const float*)d_in[10];
    const int* mask = (const int*)d_in[11];
    float* out = (float*)d_out;

    // workspace (bf16): WT3 [3][1024][1024] + WTo [1024][1024] +
    // Qh/Kh/Vh [B,H,S,Dh] + Ctx [B,H,S,Dh]  => ~75 MB
    unsigned short* WT3 = (unsigned short*)d_ws;
    unsigned short* WTo = WT3 + (size_t)3 * DIMM * DIMM;
    unsigned short* Qh  = WTo + (size_t)DIMM * DIMM;
    unsigned short* Kh  = Qh + (size_t)MT * DIMM;
    unsigned short* Vh  = Kh + (size_t)MT * DIMM;
    unsigned short* Ctx = Vh + (size_t)MT * DIMM;

    dim3 blk(256);
    dim3 tgrid(16, 16);
    wtrans_kernel<<<tgrid, blk, 0, stream>>>(Wq, WT3);
    wtrans_kernel<<<tgrid, blk, 0, stream>>>(Wk, WT3 + (size_t)DIMM * DIMM);
    wtrans_kernel<<<tgrid, blk, 0, stream>>>(Wv, WT3 + (size_t)2 * DIMM * DIMM);
    wtrans_kernel<<<tgrid, blk, 0, stream>>>(Wo, WTo);

    dim3 ggrid(8, 64);
    gemm_kernel<0><<<ggrid, blk, 0, stream>>>(q, WT3, bq, Qh);
    gemm_kernel<0><<<ggrid, blk, 0, stream>>>(k, WT3 + (size_t)DIMM * DIMM, bk, Kh);
    gemm_kernel<0><<<ggrid, blk, 0, stream>>>(v, WT3 + (size_t)2 * DIMM * DIMM, bv, Vh);

    dim3 fgrid(NH, SS / 64, BB);   // 2048 blocks
    flash_kernel<<<fgrid, blk, 0, stream>>>(Qh, Kh, Vh, mask, Ctx);

    gemm_kernel<1><<<ggrid, blk, 0, stream>>>(Ctx, WTo, bo, out);
}